// Round 6
// baseline (447.202 us; speedup 1.0000x reference)
//
#include <hip/hip_runtime.h>
#include <cstdint>

// ---- problem constants ----
#define B_   64
#define T_   218
#define TP_  228          // T + 2*PAD
#define D_   512
#define M_   13952        // B_*T_  (= 109*128, exact)
#define MT_  109          // m-tiles (128)
#define H_   4
#define DK_  128
#define N3_  1536
#define DFF_ 2048
#define KC_  5632         // conv im2col K = 11*512

typedef unsigned short u16;   // raw bf16
using short8 = __attribute__((ext_vector_type(8))) short;
using f32x4  = __attribute__((ext_vector_type(4))) float;

__device__ __forceinline__ float b2f(u16 u) {
  union { float f; uint32_t i; } v; v.i = ((uint32_t)u) << 16; return v.f;
}
__device__ __forceinline__ u16 f2b(float f) {
  union { float f; uint32_t i; } v; v.f = f;
  uint32_t r = v.i + 0x7fffu + ((v.i >> 16) & 1u);
  return (u16)(r >> 16);
}
union U8 { uint4 v; u16 u[8]; };

// async global->LDS, 16 bytes per lane; LDS dest is wave-uniform base + lane*16
__device__ __forceinline__ void gll16(const u16* g, u16* l) {
  __builtin_amdgcn_global_load_lds(
      (const __attribute__((address_space(1))) unsigned int*)g,
      (__attribute__((address_space(3))) unsigned int*)l, 16, 0, 0);
}

// LDS tile layout: [rows][32] bf16 = 64B rows. Unswizzled, a wave's 16 l15-rows
// at fixed qd hit 2 bank-groups (row parity) -> 8-way conflict. XOR swizzle:
// 16B slot' = slot ^ ((row>>1)&3) -> 16 consecutive rows cover all 8 bank-slots
// (2-way max, free). gll16 writes linearly, so the swizzle is applied by
// permuting the per-lane GLOBAL source slot: within a 16-row chunk, lane l is
// (row=l>>2, slot=l&3), so it must fetch logical slot (l&3)^((l>>3)&3).
// Reads XOR their slot with ((row>>1)&3); chunk bases are 16-row aligned so
// only the low 4 row bits matter.

// =====================================================================
// Unified 128x128 MFMA GEMM with global_load_lds staging (m97 structure)
// and XCD-aware 1D block swizzle (blockIdx%8 -> XCD heuristic).
// out[M,N] = A[M,K] (row stride sA) @ Bt[N,K]^T (row stride sB), + epilogue.
// MODE 0: bf16 out = acc+bias; v-cols also write vmpad (qkv)
// MODE 1: f32  out = acc+bias+convb+add_f             (out-proj +fsmn +x)
// MODE 2: bf16 out = relu(acc+bias)                   (ffn1)
// MODE 3: f32  out = acc+bias+add_f                   (ffn2 +x1 -> d_out)
// =====================================================================
template<int MODE>
__global__ __launch_bounds__(256, 2)
void gemm_u(const u16* __restrict__ A, int sA, const u16* __restrict__ Bt, int sB,
            const float* __restrict__ bias, const u16* __restrict__ convb,
            u16* __restrict__ vmout,
            const float* __restrict__ add_f, void* __restrict__ outp,
            int N, int K, int ntc, const float* __restrict__ masks)
{
  __shared__ u16 As[128 * 32];
  __shared__ u16 Bs[128 * 32];

  // ---- block decode: weight-stationary XCD swizzle ----
  const int xcd = blockIdx.x & 7;
  const int lin = blockIdx.x >> 3;
  const int nt = lin % ntc;            // n fastest: A-tile reuse in L2
  const int mt = xcd + 8 * (lin / ntc);// m%8 == xcd
  if (mt >= MT_) return;
  const int m0 = mt * 128, n0 = nt * 128;

  const int tid = threadIdx.x, lane = tid & 63, w = tid >> 6;
  const int wm = (w >> 1) * 64, wn = (w & 1) * 64;
  const int l15 = lane & 15, qd = lane >> 4;

  const int rl = lane >> 2;
  const int ce = ((lane & 3) ^ ((lane >> 3) & 3)) * 8;   // swizzled source slot
  const int sw8 = (qd ^ ((lane >> 1) & 3)) * 8;          // swizzled read slot
  const int r0 = m0 + w * 16 + rl, r1 = r0 + 64;
  const u16* ag0 = A + (size_t)r0 * sA + ce;
  const u16* ag1 = A + (size_t)r1 * sA + ce;
  const u16* bg0 = Bt + (size_t)(n0 + w * 16 + rl) * sB + ce;
  const u16* bg1 = bg0 + (size_t)64 * sB;
  u16* lA0 = As + w * 512;
  u16* lA1 = As + 2048 + w * 512;
  u16* lB0 = Bs + w * 512;
  u16* lB1 = Bs + 2048 + w * 512;

  const f32x4 z4 = {0.f, 0.f, 0.f, 0.f};
  f32x4 acc[4][4];
#pragma unroll
  for (int i = 0; i < 4; i++)
#pragma unroll
    for (int j = 0; j < 4; j++) acc[i][j] = z4;

  for (int k0 = 0; k0 < K; k0 += 32) {
    __syncthreads();
    gll16(ag0 + k0, lA0);
    gll16(ag1 + k0, lA1);
    gll16(bg0 + k0, lB0);
    gll16(bg1 + k0, lB1);
    __syncthreads();
    short8 af[4], bf[4];
#pragma unroll
    for (int mi = 0; mi < 4; mi++) af[mi] = *(const short8*)&As[(wm + mi * 16 + l15) * 32 + sw8];
#pragma unroll
    for (int ni = 0; ni < 4; ni++) bf[ni] = *(const short8*)&Bs[(wn + ni * 16 + l15) * 32 + sw8];
#pragma unroll
    for (int mi = 0; mi < 4; mi++)
#pragma unroll
      for (int ni = 0; ni < 4; ni++)
        acc[mi][ni] = __builtin_amdgcn_mfma_f32_16x16x32_bf16(af[mi], bf[ni], acc[mi][ni], 0, 0, 0);
  }

#pragma unroll
  for (int ni = 0; ni < 4; ni++) {
    const int c = n0 + wn + ni * 16 + l15;
    const float bv = bias[c];
#pragma unroll
    for (int mi = 0; mi < 4; mi++) {
#pragma unroll
      for (int rg = 0; rg < 4; rg++) {
        const int r = m0 + wm + mi * 16 + qd * 4 + rg;
        float v = acc[mi][ni][rg] + bv;
        if (MODE == 0) {
          ((u16*)outp)[(size_t)r * N + c] = f2b(v);
          if (c >= 1024) {   // v columns: also write masked-v into padded conv input
            const int b = r / T_, t = r - b * T_;
            vmout[((size_t)b * TP_ + t + 5) * D_ + (c - 1024)] = f2b(v * masks[r]);
          }
        } else if (MODE == 1) {
          const size_t idx = (size_t)r * N + c;
          ((float*)outp)[idx] = v + b2f(convb[idx]) + add_f[idx];
        } else if (MODE == 2) {
          ((u16*)outp)[(size_t)r * N + c] = f2b(fmaxf(v, 0.f));
        } else {
          const size_t idx = (size_t)r * N + c;
          ((float*)outp)[idx] = v + add_f[idx];
        }
      }
    }
  }
}

// =====================================================================
// FSMN conv1d: K-split fat-tile GEMM, tap-GROUP pipelined (T3+T5).
// Post-mortem r5: per-tap barriers (88) forced global read-phase/MFMA-
// phase alternation -> time = LDS(93K cyc) + MFMA(96K cyc) instead of
// max. Fix: stage B in tap-groups of 3 (4 groups 3/3/3/2), dbuf by group
// parity -> 32 barriers, ~3.3K-cyc straight-line stretches (84 MFMA +
// 33 reads/wave) where compiler interleaves next-tap reads under MFMAs;
// group staging issued BEFORE compute so the barrier drain is free.
// Geometry unchanged from r5: block = 1 batch x 128 cols, 8 waves =
// 4 positions (112x64, acc[7][4]) x 2 K-halves; grid 256 = 1 block/CU.
// s_setprio(1) around MFMA cluster (T5; phase-split now exists).
// LDS: A dbuf 2x2halfx15 = 60 chunks | B dbuf 2x(3tapx2halfx8col) = 96
// chunks; 156 KB. Epilogue: K-half reduce via LDS alias, then
// convb = (conv+vm)*mask.
// =====================================================================
__global__ __launch_bounds__(512, 2)
void conv_gemm(const u16* __restrict__ vmpad, const u16* __restrict__ Wt,
               const float* __restrict__ masks, u16* __restrict__ convb)
{
  __shared__ u16 smem[79872];   // 156 KB
  // A: chunk (h, par, c) at (h*2+par)*7680 + c*512        (c<15)
  // B: base 30720 + par*24576, chunk (ti*16 + hh*8 + q)*512

  const int nt = blockIdx.x & 3;
  const int b  = (((blockIdx.x >> 2) & 1) << 5) + (blockIdx.x >> 3);
  const int n0 = nt * 128;
  const int base = b * TP_;          // vmpad row of batch b, tap 0

  const int tid = threadIdx.x, lane = tid & 63, w = tid >> 6;
  const int h = w >> 2;              // K-half (0: i<256, 1: i>=256)
  const int p = w & 3;               // output position
  const int wm = (p >> 1) * 112;     // 112-row half of the batch
  const int pn = p & 1;              // 64-col half of the 128
  const int l15 = lane & 15, qd = lane >> 4;
  const int rl = lane >> 2;
  const int ce = ((lane & 3) ^ ((lane >> 3) & 3)) * 8;   // swizzled source slot

  // A byte-base per mi (row*64) and per-tap offset incl. XOR-swizzled slot.
  int abase[7];
#pragma unroll
  for (int mi = 0; mi < 7; mi++) abase[mi] = (wm + mi * 16 + l15) * 64;
  int toff[11];
#pragma unroll
  for (int tap = 0; tap < 11; tap++)
    toff[tap] = tap * 64 + ((qd ^ (((l15 + tap) >> 1) & 3)) << 4);
  const int swb8 = (qd ^ ((l15 >> 1) & 3)) * 8;          // B read slot

  const f32x4 z4 = {0.f, 0.f, 0.f, 0.f};
  f32x4 acc[7][4];
#pragma unroll
  for (int i = 0; i < 7; i++)
#pragma unroll
    for (int j = 0; j < 4; j++) acc[i][j] = z4;

  // A chunks for step s_ into parity pA: both halves, rows base..base+239
  // (rows 228..239 staged-but-unused, in-bounds via vmpad tail slack).
#define STAGE_A(s_, pA)                                                        \
  for (int c = w; c < 32; c += 8) {                                            \
    const int hh = c >> 4, cc = c & 15;                                        \
    if (cc < 15)                                                               \
      gll16(vmpad + (size_t)(base + cc * 16 + rl) * D_ + hh * 256 + (s_) * 32 + ce, \
            smem + (hh * 2 + (pA)) * 7680 + cc * 512);                         \
  }
  // B chunks for (step s_, taps t0_..t0_+cnt_/16-1) into parity par_.
#define STAGE_B(s_, t0_, cnt_, par_)                                           \
  for (int c = w; c < (cnt_); c += 8) {                                        \
    const int ti_ = c >> 4, r_ = c & 15, hh_ = r_ >> 3, q_ = r_ & 7;           \
    gll16(Wt + (size_t)(n0 + q_ * 16 + rl) * KC_ + (t0_ + ti_) * 512 + hh_ * 256 + (s_) * 32 + ce, \
          smem + 30720 + (par_) * 24576 + c * 512);                            \
  }

  STAGE_A(0, 0);
  STAGE_B(0, 0, 48, 0);
  __syncthreads();

#pragma unroll 1
  for (int s = 0; s < 8; ++s) {
    const char* Ab = (const char*)(smem + (h * 2 + (s & 1)) * 7680);
#pragma unroll
    for (int g = 0; g < 4; ++g) {
      const int par = (s * 4 + g) & 1;
      const int t0 = g * 3;                    // 0,3,6,9
      const int ntap = (g == 3) ? 2 : 3;
      // issue next stages before compute; drained by the end-of-group barrier
      if (g == 0 && s < 7) STAGE_A(s + 1, (s + 1) & 1);
      if (g < 3) { STAGE_B(s, (g + 1) * 3, ((g + 1) == 3) ? 32 : 48, par ^ 1); }
      else if (s < 7) { STAGE_B(s + 1, 0, 48, par ^ 1); }
      const u16* Bb = smem + 30720 + par * 24576 + h * 8 * 512;
      __builtin_amdgcn_s_setprio(1);
#pragma unroll
      for (int ti = 0; ti < 3; ++ti) {
        if (ti < ntap) {
          short8 bf[4];
#pragma unroll
          for (int ni = 0; ni < 4; ni++)
            bf[ni] = *(const short8*)&Bb[(ti * 16 + pn * 4 + ni) * 512 + l15 * 32 + swb8];
#pragma unroll
          for (int mi = 0; mi < 7; mi++) {
            short8 af = *(const short8*)(Ab + (abase[mi] + toff[t0 + ti]));
#pragma unroll
            for (int ni = 0; ni < 4; ni++)
              acc[mi][ni] = __builtin_amdgcn_mfma_f32_16x16x32_bf16(af, bf[ni], acc[mi][ni], 0, 0, 0);
          }
        }
      }
      __builtin_amdgcn_s_setprio(0);
      __syncthreads();                         // drains issued stages + reads
    }
  }
#undef STAGE_A
#undef STAGE_B

  // ---- K-half reduce through LDS (staging dead; redbuf alias) ----
  float* red = (float*)smem;
  if (h == 1) {
#pragma unroll
    for (int mi = 0; mi < 7; mi++)
#pragma unroll
      for (int ni = 0; ni < 4; ni++)
        *(f32x4*)&red[(((p * 28 + mi * 4 + ni) * 64) + lane) * 4] = acc[mi][ni];
  }
  __syncthreads();
  if (h == 0) {
#pragma unroll
    for (int mi = 0; mi < 7; mi++) {
#pragma unroll
      for (int ni = 0; ni < 4; ni++)
        acc[mi][ni] += *(const f32x4*)&red[(((p * 28 + mi * 4 + ni) * 64) + lane) * 4];
#pragma unroll
      for (int rg = 0; rg < 4; rg++) {
        const int t = wm + mi * 16 + qd * 4 + rg;    // 0..223 in batch
        if (t < T_) {
          const int r = b * T_ + t;
          const int vrow = base + t + 5;             // center-tap vmpad row
          const float m = masks[r];
#pragma unroll
          for (int ni = 0; ni < 4; ni++) {
            const int c = n0 + pn * 64 + ni * 16 + l15;
            const float vm = b2f(vmpad[(size_t)vrow * D_ + c]);
            convb[(size_t)r * D_ + c] = f2b((acc[mi][ni][rg] + vm) * m);
          }
        }
      }
    }
  }
}

// =====================================================================
// Fused attention: per (q-tile of 64, bh) block computes
// P = softmax(mask(QK^T/sqrt(dk))) entirely in LDS, then ctx = P@V.
// =====================================================================
__global__ __launch_bounds__(256, 2)
void attn_fused(const u16* __restrict__ qkv, const float* __restrict__ masks,
                u16* __restrict__ ctx)
{
  __shared__ u16 smem[29696];        // 59392 B
  __shared__ float red0[4][64];
  __shared__ float red1[4][64];
  u16* Qs = smem;                    // [64][136] phase 1
  u16* Ks = smem + 64 * 136;         // [64][136]
  u16* Ps = smem;                    // [64][232] phase 2 (aliases Qs)
  u16* Vs = smem + 64 * 232;         // [64][232]

  const int tid = threadIdx.x, lane = tid & 63, w = tid >> 6;
  const int l15 = lane & 15, qd = lane >> 4;
  const int bh = blockIdx.y, b = bh >> 2, h = bh & 3;
  const int q0 = blockIdx.x * 64;
  const uint4 uz = make_uint4(0, 0, 0, 0);

#pragma unroll
  for (int i = 0; i < 4; i++) {
    const int ch = tid + i * 256;
    const int row = ch >> 4, cg = (ch & 15) * 8;
    const int t = q0 + row;
    uint4 v = uz;
    if (t < T_) v = *(const uint4*)(qkv + ((size_t)b * T_ + t) * N3_ + h * DK_ + cg);
    *(uint4*)&Qs[row * 136 + cg] = v;
  }

  const f32x4 z4 = {0.f, 0.f, 0.f, 0.f};
  f32x4 acc[4][4];
#pragma unroll
  for (int i = 0; i < 4; i++)
#pragma unroll
    for (int j = 0; j < 4; j++) acc[i][j] = z4;

#pragma unroll
  for (int kc = 0; kc < 4; kc++) {
    __syncthreads();
#pragma unroll
    for (int i = 0; i < 4; i++) {
      const int ch = tid + i * 256;
      const int row = ch >> 4, cg = (ch & 15) * 8;
      const int t = kc * 64 + row;
      uint4 v = uz;
      if (t < T_) v = *(const uint4*)(qkv + ((size_t)b * T_ + t) * N3_ + D_ + h * DK_ + cg);
      *(uint4*)&Ks[row * 136 + cg] = v;
    }
    __syncthreads();
#pragma unroll
    for (int ks = 0; ks < 4; ks++) {
      short8 bf = *(const short8*)&Ks[(w * 16 + l15) * 136 + ks * 32 + qd * 8];
#pragma unroll
      for (int mi = 0; mi < 4; mi++) {
        short8 af = *(const short8*)&Qs[(mi * 16 + l15) * 136 + ks * 32 + qd * 8];
        acc[kc][mi] = __builtin_amdgcn_mfma_f32_16x16x32_bf16(af, bf, acc[kc][mi], 0, 0, 0);
      }
    }
  }

  const float scale = 0.08838834764831845f;  // 1/sqrt(128)
  const int colb = w * 16 + l15;
  bool valid[4];
#pragma unroll
  for (int kc = 0; kc < 4; kc++) {
    const int col = kc * 64 + colb;
    valid[kc] = (col < T_) && (masks[b * T_ + col] > 0.f);
  }

  float mx[4][4];
#pragma unroll
  for (int mi = 0; mi < 4; mi++)
#pragma unroll
    for (int rg = 0; rg < 4; rg++) {
      float m = -1e30f;
#pragma unroll
      for (int kc = 0; kc < 4; kc++)
        if (valid[kc]) m = fmaxf(m, acc[kc][mi][rg] * scale);
      for (int d = 1; d < 16; d <<= 1) m = fmaxf(m, __shfl_xor(m, d, 64));
      mx[mi][rg] = m;
    }
  if (l15 == 0) {
#pragma unroll
    for (int mi = 0; mi < 4; mi++)
#pragma unroll
      for (int rg = 0; rg < 4; rg++) red0[w][mi * 16 + qd * 4 + rg] = mx[mi][rg];
  }
  __syncthreads();
#pragma unroll
  for (int mi = 0; mi < 4; mi++)
#pragma unroll
    for (int rg = 0; rg < 4; rg++) {
      const int r = mi * 16 + qd * 4 + rg;
      mx[mi][rg] = fmaxf(fmaxf(red0[0][r], red0[1][r]), fmaxf(red0[2][r], red0[3][r]));
    }
  float sm[4][4];
#pragma unroll
  for (int mi = 0; mi < 4; mi++)
#pragma unroll
    for (int rg = 0; rg < 4; rg++) {
      float s = 0.f;
#pragma unroll
      for (int kc = 0; kc < 4; kc++)
        if (valid[kc]) s += __expf(acc[kc][mi][rg] * scale - mx[mi][rg]);
      for (int d = 1; d < 16; d <<= 1) s += __shfl_xor(s, d, 64);
      sm[mi][rg] = s;
    }
  if (l15 == 0) {
#pragma unroll
    for (int mi = 0; mi < 4; mi++)
#pragma unroll
      for (int rg = 0; rg < 4; rg++) red1[w][mi * 16 + qd * 4 + rg] = sm[mi][rg];
  }
  __syncthreads();
#pragma unroll
  for (int mi = 0; mi < 4; mi++)
#pragma unroll
    for (int rg = 0; rg < 4; rg++) {
      const int r = mi * 16 + qd * 4 + rg;
      const float inv = 1.f / (red1[0][r] + red1[1][r] + red1[2][r] + red1[3][r]);
#pragma unroll
      for (int kc = 0; kc < 4; kc++) {
        const int col = kc * 64 + colb;
        if (col < 224) {
          const float p = valid[kc] ? __expf(acc[kc][mi][rg] * scale - mx[mi][rg]) * inv : 0.f;
          Ps[r * 232 + col] = f2b(p);
        }
      }
    }

  // ---- phase 2: ctx = P @ V, per 64-d half ----
  const int kvg = tid >> 4, dg = tid & 15;
#pragma unroll
  for (int half = 0; half < 2; ++half) {
    __syncthreads();
#pragma unroll
    for (int r = 0; r < 14; ++r) {
      const int kv = r * 16 + kvg;
      ushort4 vv = make_ushort4(0, 0, 0, 0);
      if (kv < T_)
        vv = *(const ushort4*)(qkv + ((size_t)b * T_ + kv) * N3_ + 1024 + h * DK_ + half * 64 + dg * 4);
      Vs[(dg * 4 + 0) * 232 + kv] = vv.x;
      Vs[(dg * 4 + 1) * 232 + kv] = vv.y;
      Vs[(dg * 4 + 2) * 232 + kv] = vv.z;
      Vs[(dg * 4 + 3) * 232 + kv] = vv.w;
    }
    __syncthreads();
    f32x4 a2[4] = {z4, z4, z4, z4};
#pragma unroll
    for (int k0 = 0; k0 < 7; ++k0) {
      short8 af = *(const short8*)&Ps[(w * 16 + l15) * 232 + k0 * 32 + qd * 8];
#pragma unroll
      for (int nt = 0; nt < 4; ++nt) {
        short8 bf = *(const short8*)&Vs[(nt * 16 + l15) * 232 + k0 * 32 + qd * 8];
        a2[nt] = __builtin_amdgcn_mfma_f32_16x16x32_bf16(af, bf, a2[nt], 0, 0, 0);
      }
    }
    const int tb = q0 + w * 16 + qd * 4;
#pragma unroll
    for (int nt = 0; nt < 4; ++nt) {
      const int d = h * DK_ + half * 64 + nt * 16 + l15;
#pragma unroll
      for (int rg = 0; rg < 4; ++rg) {
        const int tt = tb + rg;
        if (tt < T_) ctx[((size_t)b * T_ + tt) * D_ + d] = f2b(a2[nt][rg]);
      }
    }
  }
}

// ======================= small support kernels =======================
__global__ __launch_bounds__(256)
void ln_k(const float* __restrict__ x, const float* __restrict__ wgt,
          const float* __restrict__ bia, u16* __restrict__ outp)
{
  const int lane = threadIdx.x & 63, wv = threadIdx.x >> 6;
  const size_t row = (size_t)blockIdx.x * 4 + wv;
  const float* rp = x + row * D_ + lane * 8;
  float v[8], s = 0.f, s2 = 0.f;
  float4 r0 = *(const float4*)rp;
  float4 r1 = *(const float4*)(rp + 4);
  v[0] = r0.x; v[1] = r0.y; v[2] = r0.z; v[3] = r0.w;
  v[4] = r1.x; v[5] = r1.y; v[6] = r1.z; v[7] = r1.w;
#pragma unroll
  for (int i = 0; i < 8; i++) { s += v[i]; s2 += v[i] * v[i]; }
  for (int d = 1; d < 64; d <<= 1) { s += __shfl_xor(s, d, 64); s2 += __shfl_xor(s2, d, 64); }
  const float mean = s * (1.f / 512.f);
  const float var  = s2 * (1.f / 512.f) - mean * mean;
  const float rs   = rsqrtf(var + 1e-5f);
  float4 w0 = *(const float4*)(wgt + lane * 8);
  float4 w1 = *(const float4*)(wgt + lane * 8 + 4);
  float4 b0 = *(const float4*)(bia + lane * 8);
  float4 b1 = *(const float4*)(bia + lane * 8 + 4);
  const float wv8[8] = {w0.x, w0.y, w0.z, w0.w, w1.x, w1.y, w1.z, w1.w};
  const float bv8[8] = {b0.x, b0.y, b0.z, b0.w, b1.x, b1.y, b1.z, b1.w};
  U8 o;
#pragma unroll
  for (int i = 0; i < 8; i++)
    o.u[i] = f2b((v[i] - mean) * rs * wv8[i] + bv8[i]);
  *(uint4*)(outp + row * D_ + lane * 8) = o.v;
}

// =====================================================================
// Merged prep: 4 weight transposes (fp32 KxN -> bf16 NxK), fsmn reorder
// (o,i,tap)->(o, tap*512+i), vmpad pad-row zeroing (incl. overrun slack).
// =====================================================================
__global__ __launch_bounds__(256)
void prep_all(const float* __restrict__ qkv_w, const float* __restrict__ out_w,
              const float* __restrict__ w1, const float* __restrict__ w2,
              const float* __restrict__ fsmn_w,
              u16* __restrict__ qkv_wT, u16* __restrict__ out_wT,
              u16* __restrict__ w1T, u16* __restrict__ w2T,
              u16* __restrict__ fsmnW2, u16* __restrict__ vmpad)
{
  const int bid = blockIdx.x;
  if (bid < 3072) {
    const float* src; u16* dst; int K, N, tb;
    if (bid < 768)       { src = qkv_w; dst = qkv_wT; K = 512;  N = 1536; tb = bid; }
    else if (bid < 1024) { src = out_w; dst = out_wT; K = 512;  N = 512;  tb = bid - 768; }
    else if (bid < 2048) { src = w1;    dst = w1T;    K = 512;  N = 2048; tb = bid - 1024; }
    else                 { src = w2;    dst = w2T;    K = 2048; N = 512;  tb = bid - 2048; }
    const int ktiles = K / 32;
    const int k0 = (tb % ktiles) * 32, n0 = (tb / ktiles) * 32;
    __shared__ float tile[32][33];
    const int x = threadIdx.x & 31, y = threadIdx.x >> 5;
#pragma unroll
    for (int j = 0; j < 4; j++)
      tile[y + j * 8][x] = src[(size_t)(k0 + y + j * 8) * N + n0 + x];
    __syncthreads();
#pragma unroll
    for (int j = 0; j < 4; j++)
      dst[(size_t)(n0 + y + j * 8) * K + k0 + x] = f2b(tile[x][y + j * 8]);
  } else if (bid < 4096) {
    const int idx = (bid - 3072) * 256 + threadIdx.x;   // o*512+i
    const int o = idx >> 9, i = idx & 511;
    const float* s = fsmn_w + (size_t)idx * 11;
#pragma unroll
    for (int tap = 0; tap < 11; ++tap)
      fsmnW2[(size_t)o * KC_ + tap * 512 + i] = f2b(s[tap]);
  } else {
    // zero pad rows: per-batch rows 0..4 and 223..227, plus 320-row tail slack
    const int e8 = (bid - 4096) * 256 + threadIdx.x;  // uint4 index
    const int e  = e8 * 8;
    const int c  = e & 511;
    const int pr = e >> 9;              // padded-row ordinal
    int row;
    if (pr < 640) {                     // 10 pad rows per batch
      const int b = pr / 10, j = pr % 10;
      row = b * TP_ + ((j < 5) ? j : (218 + j));
    } else {                            // tail slack rows (halo overrun)
      row = B_ * TP_ + (pr - 640);      // rows 14592..14911
    }
    *(uint4*)(vmpad + (size_t)row * D_ + c) = make_uint4(0, 0, 0, 0);
  }
}

// =====================================================================
extern "C" void kernel_launch(void* const* d_in, const int* in_sizes, int n_in,
                              void* d_out, int out_size, void* d_ws, size_t ws_size,
                              hipStream_t stream)
{
  const float* x      = (const float*)d_in[0];
  const float* masks  = (const float*)d_in[1];
  const float* ln0_w  = (const float*)d_in[2];
  const float* ln0_b  = (const float*)d_in[3];
  const float* ln1_w  = (const float*)d_in[4];
  const float* ln1_b  = (const float*)d_in[5];
  const float* qkv_w  = (const float*)d_in[6];
  const float* qkv_b  = (const float*)d_in[7];
  const float* out_w  = (const float*)d_in[8];
  const float* out_b  = (const float*)d_in[9];
  const float* fsmn_w = (const float*)d_in[10];
  const float* w1     = (const float*)d_in[11];
  const float* b1     = (const float*)d_in[12];
  const float* w2     = (const float*)d_in[13];
  const float* b2     = (const float*)d_in[14];
  float* outp = (float*)d_out;
  u16* ws   = (u16*)d_ws;

  size_t off = 0;
  u16* qkv_wT = ws + off; off += (size_t)1536 * 512;
  u16* out_wT = ws + off; off += (size_t)512 * 512;
  u16* w1T    = ws + off; off += (size_t)2048 * 512;
  u16* w2T    = ws + off; off += (size_t)512 * 2048;
  u16* fsmnW2 = ws + off; off += (size_t)512 * KC_;       // (512o, 5632k)
  u16* slotA  = ws + off; off += (size_t)M_ * 512;        // h (ln0) -> ctx
  u16* qkvb   = ws + off; off += (size_t)M_ * 1536;       // qkv; later h1 + x1
  u16* vmpad  = ws + off; off += (size_t)(B_ * TP_ + 320) * 512;  // + halo slack
  u16* regionX= ws + off;
  // regionX: convb (M*512 bf16) dead after out-proj; hid (M*2048 bf16) live
  // from ffn1 -> alias.
  u16* convb  = regionX;                                   // M*512 bf16
  u16* hid    = regionX;                                   // M*2048 bf16
  u16* h1     = qkvb;                                      // M*512 bf16
  float* x1   = (float*)(qkvb + (size_t)M_ * 512);         // M*512 fp32

  // weight prep + vmpad pad-row/slack zeroing, one launch (4096 + 30 blocks)
  prep_all<<<4126, 256, 0, stream>>>(qkv_w, out_w, w1, w2, fsmn_w,
                                     qkv_wT, out_wT, w1T, w2T, fsmnW2, vmpad);
  // ln0 -> h
  ln_k<<<M_ / 4, 256, 0, stream>>>(x, ln0_w, ln0_b, slotA);
  // qkv = h @ qkv_w + b  (bf16 out; v-cols also populate vmpad interior)
  gemm_u<0><<<8 * 14 * 12, 256, 0, stream>>>(
      slotA, 512, qkv_wT, 512, qkv_b, nullptr, vmpad, nullptr, qkvb,
      1536, 512, 12, masks);
  // fsmn conv: K-split tap-group pipelined GEMM -> convb = (conv+vm)*mask
  conv_gemm<<<256, 512, 0, stream>>>(vmpad, fsmnW2, masks, convb);
  // fused attention -> ctx in slotA
  attn_fused<<<dim3(4, 256), 256, 0, stream>>>(qkvb, masks, slotA);
  // x1 = x + ctx@out_w + out_b + convb   (fp32 out)
  gemm_u<1><<<8 * 14 * 4, 256, 0, stream>>>(
      slotA, 512, out_wT, 512, out_b, convb, nullptr, x, x1,
      512, 512, 4, masks);
  // ffn
  ln_k<<<M_ / 4, 256, 0, stream>>>(x1, ln1_w, ln1_b, h1);
  gemm_u<2><<<8 * 14 * 16, 256, 0, stream>>>(
      h1, 512, w1T, 512, b1, nullptr, nullptr, nullptr, hid,
      2048, 512, 16, nullptr);
  gemm_u<3><<<8 * 14 * 4, 256, 0, stream>>>(
      hid, 2048, w2T, 2048, b2, nullptr, nullptr, x1, outp,
      512, 2048, 4, nullptr);
}

// Round 7
// 436.393 us; speedup vs baseline: 1.0248x; 1.0248x over previous
//
#include <hip/hip_runtime.h>
#include <cstdint>

// ---- problem constants ----
#define B_   64
#define T_   218
#define TP_  228          // T + 2*PAD
#define D_   512
#define M_   13952        // B_*T_  (= 109*128, exact)
#define MT_  109          // m-tiles (128)
#define H_   4
#define DK_  128
#define N3_  1536
#define DFF_ 2048
#define KC_  5632         // conv im2col K = 11*512

typedef unsigned short u16;   // raw bf16
using short8 = __attribute__((ext_vector_type(8))) short;
using f32x4  = __attribute__((ext_vector_type(4))) float;

__device__ __forceinline__ float b2f(u16 u) {
  union { float f; uint32_t i; } v; v.i = ((uint32_t)u) << 16; return v.f;
}
__device__ __forceinline__ u16 f2b(float f) {
  union { float f; uint32_t i; } v; v.f = f;
  uint32_t r = v.i + 0x7fffu + ((v.i >> 16) & 1u);
  return (u16)(r >> 16);
}
union U8 { uint4 v; u16 u[8]; };

// async global->LDS, 16 bytes per lane; LDS dest is wave-uniform base + lane*16
__device__ __forceinline__ void gll16(const u16* g, u16* l) {
  __builtin_amdgcn_global_load_lds(
      (const __attribute__((address_space(1))) unsigned int*)g,
      (__attribute__((address_space(3))) unsigned int*)l, 16, 0, 0);
}

// LDS tile layout: [rows][32] bf16 = 64B rows. Unswizzled, a wave's 16 l15-rows
// at fixed qd hit 2 bank-groups (row parity) -> 8-way conflict. XOR swizzle:
// 16B slot' = slot ^ ((row>>1)&3) -> 16 consecutive rows cover all 8 bank-slots
// (2-way max, free). gll16 writes linearly, so the swizzle is applied by
// permuting the per-lane GLOBAL source slot: within a 16-row chunk, lane l is
// (row=l>>2, slot=l&3), so it must fetch logical slot (l&3)^((l>>3)&3).
// Reads XOR their slot with ((row>>1)&3); chunk bases are 16-row aligned so
// only the low 4 row bits matter.

// =====================================================================
// Unified 128x128 MFMA GEMM, 2-deep counted-vmcnt pipeline (T3+T4 min).
// Round-7 change: the old `sync; gll16x4; sync` loop drained vmcnt(0) on
// just-issued loads every K-step, exposing full L2 latency 16-64x per
// block. Now: double-buffered LDS; stage(i+2) issued after the post-
// compute barrier; waits are raw `s_barrier` + counted `s_waitcnt
// vmcnt(4)` (loads waited on were issued >=1 iteration earlier -> ~free).
// Safety: "memory"-clobbered asm + sched_barrier(0) fences; stage(i+2)
// only writes a buffer all waves finished reading (barrier #2); each
// wave's ds_reads complete before its last MFMA (compiler lgkmcnt), so
// no read can race the later gll16 write.
// out[M,N] = A[M,K] (row stride sA) @ Bt[N,K]^T (row stride sB), + epilogue.
// MODE 0: bf16 out = acc+bias; v-cols also write vmpad (qkv)
// MODE 1: f32  out = acc+bias+convb+add_f             (out-proj +fsmn +x)
// MODE 2: bf16 out = relu(acc+bias)                   (ffn1)
// MODE 3: f32  out = acc+bias+add_f                   (ffn2 +x1 -> d_out)
// =====================================================================
template<int MODE>
__global__ __launch_bounds__(256, 2)
void gemm_u(const u16* __restrict__ A, int sA, const u16* __restrict__ Bt, int sB,
            const float* __restrict__ bias, const u16* __restrict__ convb,
            u16* __restrict__ vmout,
            const float* __restrict__ add_f, void* __restrict__ outp,
            int N, int K, int ntc, const float* __restrict__ masks)
{
  __shared__ u16 As[2 * 128 * 32];   // dbuf: 16 KB
  __shared__ u16 Bs[2 * 128 * 32];

  // ---- block decode: weight-stationary XCD swizzle ----
  const int xcd = blockIdx.x & 7;
  const int lin = blockIdx.x >> 3;
  const int nt = lin % ntc;            // n fastest: A-tile reuse in L2
  const int mt = xcd + 8 * (lin / ntc);// m%8 == xcd
  if (mt >= MT_) return;
  const int m0 = mt * 128, n0 = nt * 128;

  const int tid = threadIdx.x, lane = tid & 63, w = tid >> 6;
  const int wm = (w >> 1) * 64, wn = (w & 1) * 64;
  const int l15 = lane & 15, qd = lane >> 4;

  const int rl = lane >> 2;
  const int ce = ((lane & 3) ^ ((lane >> 3) & 3)) * 8;   // swizzled source slot
  const int sw8 = (qd ^ ((lane >> 1) & 3)) * 8;          // swizzled read slot
  const int r0 = m0 + w * 16 + rl, r1 = r0 + 64;
  const u16* ag0 = A + (size_t)r0 * sA + ce;
  const u16* ag1 = A + (size_t)r1 * sA + ce;
  const u16* bg0 = Bt + (size_t)(n0 + w * 16 + rl) * sB + ce;
  const u16* bg1 = bg0 + (size_t)64 * sB;

  const f32x4 z4 = {0.f, 0.f, 0.f, 0.f};
  f32x4 acc[4][4];
#pragma unroll
  for (int i = 0; i < 4; i++)
#pragma unroll
    for (int j = 0; j < 4; j++) acc[i][j] = z4;

  const int nk = K >> 5;
  // prologue: stage steps 0 (buf0) and 1 (buf1)
  gll16(ag0, As + w * 512);
  gll16(ag1, As + 2048 + w * 512);
  gll16(bg0, Bs + w * 512);
  gll16(bg1, Bs + 2048 + w * 512);
  gll16(ag0 + 32, As + 4096 + w * 512);
  gll16(ag1 + 32, As + 4096 + 2048 + w * 512);
  gll16(bg0 + 32, Bs + 4096 + w * 512);
  gll16(bg1 + 32, Bs + 4096 + 2048 + w * 512);

#pragma unroll 1
  for (int i = 0; i < nk; ++i) {
    if (i < nk - 1) asm volatile("s_waitcnt vmcnt(4)" ::: "memory");
    else            asm volatile("s_waitcnt vmcnt(0)" ::: "memory");
    __builtin_amdgcn_s_barrier();          // buf(i&1) staged on all waves
    __builtin_amdgcn_sched_barrier(0);
    const int bo = (i & 1) * 4096;
    short8 af[4], bf[4];
#pragma unroll
    for (int mi = 0; mi < 4; mi++) af[mi] = *(const short8*)&As[bo + (wm + mi * 16 + l15) * 32 + sw8];
#pragma unroll
    for (int ni = 0; ni < 4; ni++) bf[ni] = *(const short8*)&Bs[bo + (wn + ni * 16 + l15) * 32 + sw8];
#pragma unroll
    for (int mi = 0; mi < 4; mi++)
#pragma unroll
      for (int ni = 0; ni < 4; ni++)
        acc[mi][ni] = __builtin_amdgcn_mfma_f32_16x16x32_bf16(af[mi], bf[ni], acc[mi][ni], 0, 0, 0);
    __builtin_amdgcn_sched_barrier(0);
    __builtin_amdgcn_s_barrier();          // all waves done reading buf(i&1)
    __builtin_amdgcn_sched_barrier(0);
    if (i + 2 < nk) {                      // refill the buffer just consumed
      const int k2 = (i + 2) << 5;
      gll16(ag0 + k2, As + bo + w * 512);
      gll16(ag1 + k2, As + bo + 2048 + w * 512);
      gll16(bg0 + k2, Bs + bo + w * 512);
      gll16(bg1 + k2, Bs + bo + 2048 + w * 512);
    }
  }

#pragma unroll
  for (int ni = 0; ni < 4; ni++) {
    const int c = n0 + wn + ni * 16 + l15;
    const float bv = bias[c];
#pragma unroll
    for (int mi = 0; mi < 4; mi++) {
#pragma unroll
      for (int rg = 0; rg < 4; rg++) {
        const int r = m0 + wm + mi * 16 + qd * 4 + rg;
        float v = acc[mi][ni][rg] + bv;
        if (MODE == 0) {
          ((u16*)outp)[(size_t)r * N + c] = f2b(v);
          if (c >= 1024) {   // v columns: also write masked-v into padded conv input
            const int b = r / T_, t = r - b * T_;
            vmout[((size_t)b * TP_ + t + 5) * D_ + (c - 1024)] = f2b(v * masks[r]);
          }
        } else if (MODE == 1) {
          const size_t idx = (size_t)r * N + c;
          ((float*)outp)[idx] = v + b2f(convb[idx]) + add_f[idx];
        } else if (MODE == 2) {
          ((u16*)outp)[(size_t)r * N + c] = f2b(fmaxf(v, 0.f));
        } else {
          const size_t idx = (size_t)r * N + c;
          ((float*)outp)[idx] = v + add_f[idx];
        }
      }
    }
  }
}

// =====================================================================
// FSMN conv1d: K-split fat-tile GEMM, tap-GROUP pipelined (T3+T5).
// (Best known: ~87 us. r5/r6 showed the LDS/MFMA serialization is
// invariant to barrier restructuring at this geometry; parked.)
// Block = 1 batch x 128 cols, 8 waves = 4 positions (112x64, acc[7][4])
// x 2 K-halves; grid 256 = 1 block/CU. B staged in tap-groups of 3
// (4 groups 3/3/3/2) dbuf by parity; A dbuf per 32-k step. setprio
// around MFMA cluster. Epilogue: K-half reduce via LDS alias, then
// convb = (conv+vm)*mask.
// =====================================================================
__global__ __launch_bounds__(512, 2)
void conv_gemm(const u16* __restrict__ vmpad, const u16* __restrict__ Wt,
               const float* __restrict__ masks, u16* __restrict__ convb)
{
  __shared__ u16 smem[79872];   // 156 KB
  // A: chunk (h, par, c) at (h*2+par)*7680 + c*512        (c<15)
  // B: base 30720 + par*24576, chunk (ti*16 + hh*8 + q)*512

  const int nt = blockIdx.x & 3;
  const int b  = (((blockIdx.x >> 2) & 1) << 5) + (blockIdx.x >> 3);
  const int n0 = nt * 128;
  const int base = b * TP_;          // vmpad row of batch b, tap 0

  const int tid = threadIdx.x, lane = tid & 63, w = tid >> 6;
  const int h = w >> 2;              // K-half (0: i<256, 1: i>=256)
  const int p = w & 3;               // output position
  const int wm = (p >> 1) * 112;     // 112-row half of the batch
  const int pn = p & 1;              // 64-col half of the 128
  const int l15 = lane & 15, qd = lane >> 4;
  const int rl = lane >> 2;
  const int ce = ((lane & 3) ^ ((lane >> 3) & 3)) * 8;   // swizzled source slot

  // A byte-base per mi (row*64) and per-tap offset incl. XOR-swizzled slot.
  int abase[7];
#pragma unroll
  for (int mi = 0; mi < 7; mi++) abase[mi] = (wm + mi * 16 + l15) * 64;
  int toff[11];
#pragma unroll
  for (int tap = 0; tap < 11; tap++)
    toff[tap] = tap * 64 + ((qd ^ (((l15 + tap) >> 1) & 3)) << 4);
  const int swb8 = (qd ^ ((l15 >> 1) & 3)) * 8;          // B read slot

  const f32x4 z4 = {0.f, 0.f, 0.f, 0.f};
  f32x4 acc[7][4];
#pragma unroll
  for (int i = 0; i < 7; i++)
#pragma unroll
    for (int j = 0; j < 4; j++) acc[i][j] = z4;

  // A chunks for step s_ into parity pA: both halves, rows base..base+239
  // (rows 228..239 staged-but-unused, in-bounds via vmpad tail slack).
#define STAGE_A(s_, pA)                                                        \
  for (int c = w; c < 32; c += 8) {                                            \
    const int hh = c >> 4, cc = c & 15;                                        \
    if (cc < 15)                                                               \
      gll16(vmpad + (size_t)(base + cc * 16 + rl) * D_ + hh * 256 + (s_) * 32 + ce, \
            smem + (hh * 2 + (pA)) * 7680 + cc * 512);                         \
  }
  // B chunks for (step s_, taps t0_..t0_+cnt_/16-1) into parity par_.
#define STAGE_B(s_, t0_, cnt_, par_)                                           \
  for (int c = w; c < (cnt_); c += 8) {                                        \
    const int ti_ = c >> 4, r_ = c & 15, hh_ = r_ >> 3, q_ = r_ & 7;           \
    gll16(Wt + (size_t)(n0 + q_ * 16 + rl) * KC_ + (t0_ + ti_) * 512 + hh_ * 256 + (s_) * 32 + ce, \
          smem + 30720 + (par_) * 24576 + c * 512);                            \
  }

  STAGE_A(0, 0);
  STAGE_B(0, 0, 48, 0);
  __syncthreads();

#pragma unroll 1
  for (int s = 0; s < 8; ++s) {
    const char* Ab = (const char*)(smem + (h * 2 + (s & 1)) * 7680);
#pragma unroll
    for (int g = 0; g < 4; ++g) {
      const int par = (s * 4 + g) & 1;
      const int t0 = g * 3;                    // 0,3,6,9
      const int ntap = (g == 3) ? 2 : 3;
      // issue next stages before compute; drained by the end-of-group barrier
      if (g == 0 && s < 7) STAGE_A(s + 1, (s + 1) & 1);
      if (g < 3) { STAGE_B(s, (g + 1) * 3, ((g + 1) == 3) ? 32 : 48, par ^ 1); }
      else if (s < 7) { STAGE_B(s + 1, 0, 48, par ^ 1); }
      const u16* Bb = smem + 30720 + par * 24576 + h * 8 * 512;
      __builtin_amdgcn_s_setprio(1);
#pragma unroll
      for (int ti = 0; ti < 3; ++ti) {
        if (ti < ntap) {
          short8 bf[4];
#pragma unroll
          for (int ni = 0; ni < 4; ni++)
            bf[ni] = *(const short8*)&Bb[(ti * 16 + pn * 4 + ni) * 512 + l15 * 32 + swb8];
#pragma unroll
          for (int mi = 0; mi < 7; mi++) {
            short8 af = *(const short8*)(Ab + (abase[mi] + toff[t0 + ti]));
#pragma unroll
            for (int ni = 0; ni < 4; ni++)
              acc[mi][ni] = __builtin_amdgcn_mfma_f32_16x16x32_bf16(af, bf[ni], acc[mi][ni], 0, 0, 0);
          }
        }
      }
      __builtin_amdgcn_s_setprio(0);
      __syncthreads();                         // drains issued stages + reads
    }
  }
#undef STAGE_A
#undef STAGE_B

  // ---- K-half reduce through LDS (staging dead; redbuf alias) ----
  float* red = (float*)smem;
  if (h == 1) {
#pragma unroll
    for (int mi = 0; mi < 7; mi++)
#pragma unroll
      for (int ni = 0; ni < 4; ni++)
        *(f32x4*)&red[(((p * 28 + mi * 4 + ni) * 64) + lane) * 4] = acc[mi][ni];
  }
  __syncthreads();
  if (h == 0) {
#pragma unroll
    for (int mi = 0; mi < 7; mi++) {
#pragma unroll
      for (int ni = 0; ni < 4; ni++)
        acc[mi][ni] += *(const f32x4*)&red[(((p * 28 + mi * 4 + ni) * 64) + lane) * 4];
#pragma unroll
      for (int rg = 0; rg < 4; rg++) {
        const int t = wm + mi * 16 + qd * 4 + rg;    // 0..223 in batch
        if (t < T_) {
          const int r = b * T_ + t;
          const int vrow = base + t + 5;             // center-tap vmpad row
          const float m = masks[r];
#pragma unroll
          for (int ni = 0; ni < 4; ni++) {
            const int c = n0 + pn * 64 + ni * 16 + l15;
            const float vm = b2f(vmpad[(size_t)vrow * D_ + c]);
            convb[(size_t)r * D_ + c] = f2b((acc[mi][ni][rg] + vm) * m);
          }
        }
      }
    }
  }
}

// =====================================================================
// Fused attention: per (q-tile of 64, bh) block computes
// P = softmax(mask(QK^T/sqrt(dk))) entirely in LDS, then ctx = P@V.
// =====================================================================
__global__ __launch_bounds__(256, 2)
void attn_fused(const u16* __restrict__ qkv, const float* __restrict__ masks,
                u16* __restrict__ ctx)
{
  __shared__ u16 smem[29696];        // 59392 B
  __shared__ float red0[4][64];
  __shared__ float red1[4][64];
  u16* Qs = smem;                    // [64][136] phase 1
  u16* Ks = smem + 64 * 136;         // [64][136]
  u16* Ps = smem;                    // [64][232] phase 2 (aliases Qs)
  u16* Vs = smem + 64 * 232;         // [64][232]

  const int tid = threadIdx.x, lane = tid & 63, w = tid >> 6;
  const int l15 = lane & 15, qd = lane >> 4;
  const int bh = blockIdx.y, b = bh >> 2, h = bh & 3;
  const int q0 = blockIdx.x * 64;
  const uint4 uz = make_uint4(0, 0, 0, 0);

#pragma unroll
  for (int i = 0; i < 4; i++) {
    const int ch = tid + i * 256;
    const int row = ch >> 4, cg = (ch & 15) * 8;
    const int t = q0 + row;
    uint4 v = uz;
    if (t < T_) v = *(const uint4*)(qkv + ((size_t)b * T_ + t) * N3_ + h * DK_ + cg);
    *(uint4*)&Qs[row * 136 + cg] = v;
  }

  const f32x4 z4 = {0.f, 0.f, 0.f, 0.f};
  f32x4 acc[4][4];
#pragma unroll
  for (int i = 0; i < 4; i++)
#pragma unroll
    for (int j = 0; j < 4; j++) acc[i][j] = z4;

#pragma unroll
  for (int kc = 0; kc < 4; kc++) {
    __syncthreads();
#pragma unroll
    for (int i = 0; i < 4; i++) {
      const int ch = tid + i * 256;
      const int row = ch >> 4, cg = (ch & 15) * 8;
      const int t = kc * 64 + row;
      uint4 v = uz;
      if (t < T_) v = *(const uint4*)(qkv + ((size_t)b * T_ + t) * N3_ + D_ + h * DK_ + cg);
      *(uint4*)&Ks[row * 136 + cg] = v;
    }
    __syncthreads();
#pragma unroll
    for (int ks = 0; ks < 4; ks++) {
      short8 bf = *(const short8*)&Ks[(w * 16 + l15) * 136 + ks * 32 + qd * 8];
#pragma unroll
      for (int mi = 0; mi < 4; mi++) {
        short8 af = *(const short8*)&Qs[(mi * 16 + l15) * 136 + ks * 32 + qd * 8];
        acc[kc][mi] = __builtin_amdgcn_mfma_f32_16x16x32_bf16(af, bf, acc[kc][mi], 0, 0, 0);
      }
    }
  }

  const float scale = 0.08838834764831845f;  // 1/sqrt(128)
  const int colb = w * 16 + l15;
  bool valid[4];
#pragma unroll
  for (int kc = 0; kc < 4; kc++) {
    const int col = kc * 64 + colb;
    valid[kc] = (col < T_) && (masks[b * T_ + col] > 0.f);
  }

  float mx[4][4];
#pragma unroll
  for (int mi = 0; mi < 4; mi++)
#pragma unroll
    for (int rg = 0; rg < 4; rg++) {
      float m = -1e30f;
#pragma unroll
      for (int kc = 0; kc < 4; kc++)
        if (valid[kc]) m = fmaxf(m, acc[kc][mi][rg] * scale);
      for (int d = 1; d < 16; d <<= 1) m = fmaxf(m, __shfl_xor(m, d, 64));
      mx[mi][rg] = m;
    }
  if (l15 == 0) {
#pragma unroll
    for (int mi = 0; mi < 4; mi++)
#pragma unroll
      for (int rg = 0; rg < 4; rg++) red0[w][mi * 16 + qd * 4 + rg] = mx[mi][rg];
  }
  __syncthreads();
#pragma unroll
  for (int mi = 0; mi < 4; mi++)
#pragma unroll
    for (int rg = 0; rg < 4; rg++) {
      const int r = mi * 16 + qd * 4 + rg;
      mx[mi][rg] = fmaxf(fmaxf(red0[0][r], red0[1][r]), fmaxf(red0[2][r], red0[3][r]));
    }
  float sm[4][4];
#pragma unroll
  for (int mi = 0; mi < 4; mi++)
#pragma unroll
    for (int rg = 0; rg < 4; rg++) {
      float s = 0.f;
#pragma unroll
      for (int kc = 0; kc < 4; kc++)
        if (valid[kc]) s += __expf(acc[kc][mi][rg] * scale - mx[mi][rg]);
      for (int d = 1; d < 16; d <<= 1) s += __shfl_xor(s, d, 64);
      sm[mi][rg] = s;
    }
  if (l15 == 0) {
#pragma unroll
    for (int mi = 0; mi < 4; mi++)
#pragma unroll
      for (int rg = 0; rg < 4; rg++) red1[w][mi * 16 + qd * 4 + rg] = sm[mi][rg];
  }
  __syncthreads();
#pragma unroll
  for (int mi = 0; mi < 4; mi++)
#pragma unroll
    for (int rg = 0; rg < 4; rg++) {
      const int r = mi * 16 + qd * 4 + rg;
      const float inv = 1.f / (red1[0][r] + red1[1][r] + red1[2][r] + red1[3][r]);
#pragma unroll
      for (int kc = 0; kc < 4; kc++) {
        const int col = kc * 64 + colb;
        if (col < 224) {
          const float p = valid[kc] ? __expf(acc[kc][mi][rg] * scale - mx[mi][rg]) * inv : 0.f;
          Ps[r * 232 + col] = f2b(p);
        }
      }
    }

  // ---- phase 2: ctx = P @ V, per 64-d half ----
  const int kvg = tid >> 4, dg = tid & 15;
#pragma unroll
  for (int half = 0; half < 2; ++half) {
    __syncthreads();
#pragma unroll
    for (int r = 0; r < 14; ++r) {
      const int kv = r * 16 + kvg;
      ushort4 vv = make_ushort4(0, 0, 0, 0);
      if (kv < T_)
        vv = *(const ushort4*)(qkv + ((size_t)b * T_ + kv) * N3_ + 1024 + h * DK_ + half * 64 + dg * 4);
      Vs[(dg * 4 + 0) * 232 + kv] = vv.x;
      Vs[(dg * 4 + 1) * 232 + kv] = vv.y;
      Vs[(dg * 4 + 2) * 232 + kv] = vv.z;
      Vs[(dg * 4 + 3) * 232 + kv] = vv.w;
    }
    __syncthreads();
    f32x4 a2[4] = {z4, z4, z4, z4};
#pragma unroll
    for (int k0 = 0; k0 < 7; ++k0) {
      short8 af = *(const short8*)&Ps[(w * 16 + l15) * 232 + k0 * 32 + qd * 8];
#pragma unroll
      for (int nt = 0; nt < 4; ++nt) {
        short8 bf = *(const short8*)&Vs[(nt * 16 + l15) * 232 + k0 * 32 + qd * 8];
        a2[nt] = __builtin_amdgcn_mfma_f32_16x16x32_bf16(af, bf, a2[nt], 0, 0, 0);
      }
    }
    const int tb = q0 + w * 16 + qd * 4;
#pragma unroll
    for (int nt = 0; nt < 4; ++nt) {
      const int d = h * DK_ + half * 64 + nt * 16 + l15;
#pragma unroll
      for (int rg = 0; rg < 4; ++rg) {
        const int tt = tb + rg;
        if (tt < T_) ctx[((size_t)b * T_ + tt) * D_ + d] = f2b(a2[nt][rg]);
      }
    }
  }
}

// ======================= small support kernels =======================
__global__ __launch_bounds__(256)
void ln_k(const float* __restrict__ x, const float* __restrict__ wgt,
          const float* __restrict__ bia, u16* __restrict__ outp)
{
  const int lane = threadIdx.x & 63, wv = threadIdx.x >> 6;
  const size_t row = (size_t)blockIdx.x * 4 + wv;
  const float* rp = x + row * D_ + lane * 8;
  float v[8], s = 0.f, s2 = 0.f;
  float4 r0 = *(const float4*)rp;
  float4 r1 = *(const float4*)(rp + 4);
  v[0] = r0.x; v[1] = r0.y; v[2] = r0.z; v[3] = r0.w;
  v[4] = r1.x; v[5] = r1.y; v[6] = r1.z; v[7] = r1.w;
#pragma unroll
  for (int i = 0; i < 8; i++) { s += v[i]; s2 += v[i] * v[i]; }
  for (int d = 1; d < 64; d <<= 1) { s += __shfl_xor(s, d, 64); s2 += __shfl_xor(s2, d, 64); }
  const float mean = s * (1.f / 512.f);
  const float var  = s2 * (1.f / 512.f) - mean * mean;
  const float rs   = rsqrtf(var + 1e-5f);
  float4 w0 = *(const float4*)(wgt + lane * 8);
  float4 w1 = *(const float4*)(wgt + lane * 8 + 4);
  float4 b0 = *(const float4*)(bia + lane * 8);
  float4 b1 = *(const float4*)(bia + lane * 8 + 4);
  const float wv8[8] = {w0.x, w0.y, w0.z, w0.w, w1.x, w1.y, w1.z, w1.w};
  const float bv8[8] = {b0.x, b0.y, b0.z, b0.w, b1.x, b1.y, b1.z, b1.w};
  U8 o;
#pragma unroll
  for (int i = 0; i < 8; i++)
    o.u[i] = f2b((v[i] - mean) * rs * wv8[i] + bv8[i]);
  *(uint4*)(outp + row * D_ + lane * 8) = o.v;
}

// =====================================================================
// Merged prep: 4 weight transposes (fp32 KxN -> bf16 NxK), fsmn reorder
// (o,i,tap)->(o, tap*512+i), vmpad pad-row zeroing (incl. overrun slack).
// =====================================================================
__global__ __launch_bounds__(256)
void prep_all(const float* __restrict__ qkv_w, const float* __restrict__ out_w,
              const float* __restrict__ w1, const float* __restrict__ w2,
              const float* __restrict__ fsmn_w,
              u16* __restrict__ qkv_wT, u16* __restrict__ out_wT,
              u16* __restrict__ w1T, u16* __restrict__ w2T,
              u16* __restrict__ fsmnW2, u16* __restrict__ vmpad)
{
  const int bid = blockIdx.x;
  if (bid < 3072) {
    const float* src; u16* dst; int K, N, tb;
    if (bid < 768)       { src = qkv_w; dst = qkv_wT; K = 512;  N = 1536; tb = bid; }
    else if (bid < 1024) { src = out_w; dst = out_wT; K = 512;  N = 512;  tb = bid - 768; }
    else if (bid < 2048) { src = w1;    dst = w1T;    K = 512;  N = 2048; tb = bid - 1024; }
    else                 { src = w2;    dst = w2T;    K = 2048; N = 512;  tb = bid - 2048; }
    const int ktiles = K / 32;
    const int k0 = (tb % ktiles) * 32, n0 = (tb / ktiles) * 32;
    __shared__ float tile[32][33];
    const int x = threadIdx.x & 31, y = threadIdx.x >> 5;
#pragma unroll
    for (int j = 0; j < 4; j++)
      tile[y + j * 8][x] = src[(size_t)(k0 + y + j * 8) * N + n0 + x];
    __syncthreads();
#pragma unroll
    for (int j = 0; j < 4; j++)
      dst[(size_t)(n0 + y + j * 8) * K + k0 + x] = f2b(tile[x][y + j * 8]);
  } else if (bid < 4096) {
    const int idx = (bid - 3072) * 256 + threadIdx.x;   // o*512+i
    const int o = idx >> 9, i = idx & 511;
    const float* s = fsmn_w + (size_t)idx * 11;
#pragma unroll
    for (int tap = 0; tap < 11; ++tap)
      fsmnW2[(size_t)o * KC_ + tap * 512 + i] = f2b(s[tap]);
  } else {
    // zero pad rows: per-batch rows 0..4 and 223..227, plus 320-row tail slack
    const int e8 = (bid - 4096) * 256 + threadIdx.x;  // uint4 index
    const int e  = e8 * 8;
    const int c  = e & 511;
    const int pr = e >> 9;              // padded-row ordinal
    int row;
    if (pr < 640) {                     // 10 pad rows per batch
      const int b = pr / 10, j = pr % 10;
      row = b * TP_ + ((j < 5) ? j : (218 + j));
    } else {                            // tail slack rows (halo overrun)
      row = B_ * TP_ + (pr - 640);      // rows 14592..14911
    }
    *(uint4*)(vmpad + (size_t)row * D_ + c) = make_uint4(0, 0, 0, 0);
  }
}

// =====================================================================
extern "C" void kernel_launch(void* const* d_in, const int* in_sizes, int n_in,
                              void* d_out, int out_size, void* d_ws, size_t ws_size,
                              hipStream_t stream)
{
  const float* x      = (const float*)d_in[0];
  const float* masks  = (const float*)d_in[1];
  const float* ln0_w  = (const float*)d_in[2];
  const float* ln0_b  = (const float*)d_in[3];
  const float* ln1_w  = (const float*)d_in[4];
  const float* ln1_b  = (const float*)d_in[5];
  const float* qkv_w  = (const float*)d_in[6];
  const float* qkv_b  = (const float*)d_in[7];
  const float* out_w  = (const float*)d_in[8];
  const float* out_b  = (const float*)d_in[9];
  const float* fsmn_w = (const float*)d_in[10];
  const float* w1     = (const float*)d_in[11];
  const float* b1     = (const float*)d_in[12];
  const float* w2     = (const float*)d_in[13];
  const float* b2     = (const float*)d_in[14];
  float* outp = (float*)d_out;
  u16* ws   = (u16*)d_ws;

  size_t off = 0;
  u16* qkv_wT = ws + off; off += (size_t)1536 * 512;
  u16* out_wT = ws + off; off += (size_t)512 * 512;
  u16* w1T    = ws + off; off += (size_t)2048 * 512;
  u16* w2T    = ws + off; off += (size_t)512 * 2048;
  u16* fsmnW2 = ws + off; off += (size_t)512 * KC_;       // (512o, 5632k)
  u16* slotA  = ws + off; off += (size_t)M_ * 512;        // h (ln0) -> ctx
  u16* qkvb   = ws + off; off += (size_t)M_ * 1536;       // qkv; later h1 + x1
  u16* vmpad  = ws + off; off += (size_t)(B_ * TP_ + 320) * 512;  // + halo slack
  u16* regionX= ws + off;
  // regionX: convb (M*512 bf16) dead after out-proj; hid (M*2048 bf16) live
  // from ffn1 -> alias.
  u16* convb  = regionX;                                   // M*512 bf16
  u16* hid    = regionX;                                   // M*2048 bf16
  u16* h1     = qkvb;                                      // M*512 bf16
  float* x1   = (float*)(qkvb + (size_t)M_ * 512);         // M*512 fp32

  // weight prep + vmpad pad-row/slack zeroing, one launch (4096 + 30 blocks)
  prep_all<<<4126, 256, 0, stream>>>(qkv_w, out_w, w1, w2, fsmn_w,
                                     qkv_wT, out_wT, w1T, w2T, fsmnW2, vmpad);
  // ln0 -> h
  ln_k<<<M_ / 4, 256, 0, stream>>>(x, ln0_w, ln0_b, slotA);
  // qkv = h @ qkv_w + b  (bf16 out; v-cols also populate vmpad interior)
  gemm_u<0><<<8 * 14 * 12, 256, 0, stream>>>(
      slotA, 512, qkv_wT, 512, qkv_b, nullptr, vmpad, nullptr, qkvb,
      1536, 512, 12, masks);
  // fsmn conv: K-split tap-group pipelined GEMM -> convb = (conv+vm)*mask
  conv_gemm<<<256, 512, 0, stream>>>(vmpad, fsmnW2, masks, convb);
  // fused attention -> ctx in slotA
  attn_fused<<<dim3(4, 256), 256, 0, stream>>>(qkvb, masks, slotA);
  // x1 = x + ctx@out_w + out_b + convb   (fp32 out)
  gemm_u<1><<<8 * 14 * 4, 256, 0, stream>>>(
      slotA, 512, out_wT, 512, out_b, convb, nullptr, x, x1,
      512, 512, 4, masks);
  // ffn
  ln_k<<<M_ / 4, 256, 0, stream>>>(x1, ln1_w, ln1_b, h1);
  gemm_u<2><<<8 * 14 * 16, 256, 0, stream>>>(
      h1, 512, w1T, 512, b1, nullptr, nullptr, nullptr, hid,
      2048, 512, 16, nullptr);
  gemm_u<3><<<8 * 14 * 4, 256, 0, stream>>>(
      hid, 2048, w2T, 2048, b2, nullptr, nullptr, x1, outp,
      512, 2048, 4, nullptr);
}